// Round 9
// baseline (8429.420 us; speedup 1.0000x reference)
//
#include <hip/hip_runtime.h>
#include <stdint.h>

typedef __bf16 bf16x8 __attribute__((ext_vector_type(8)));
typedef float floatx4 __attribute__((ext_vector_type(4)));
typedef unsigned int u32x4 __attribute__((ext_vector_type(4)));

#define T_STEPS 512
#define BATCH   64
#define HDIM    512
#define NGATE   1024   // 2*H
#define IDIM    512
#define RBLOCKS 32     // recurrent blocks, 16 cols each

__device__ __forceinline__ unsigned short f2bf(float f) {
  unsigned int u = __builtin_bit_cast(unsigned int, f);
  u += 0x7fffu + ((u >> 16) & 1u);
  return (unsigned short)(u >> 16);
}
__device__ __forceinline__ float bf2f(unsigned short s) {
  unsigned int u = ((unsigned int)s) << 16;
  return __builtin_bit_cast(float, u);
}

// ---------------- fp32 -> bf16 hi + lo residual ----------------
__global__ void cvt_split_kernel(const float4* __restrict__ src,
                                 ushort4* __restrict__ hi, ushort4* __restrict__ lo, int n4) {
  int i = blockIdx.x * blockDim.x + threadIdx.x;
  if (i >= n4) return;
  float4 v = src[i];
  ushort4 h, l;
  h.x = f2bf(v.x); l.x = f2bf(v.x - bf2f(h.x));
  h.y = f2bf(v.y); l.y = f2bf(v.y - bf2f(h.y));
  h.z = f2bf(v.z); l.z = f2bf(v.z - bf2f(h.z));
  h.w = f2bf(v.w); l.w = f2bf(v.w - bf2f(h.w));
  hi[i] = h; lo[i] = l;
}

// biasc[i] = bih[i] + (i < H ? bhh[i] : 0)
__global__ void bias_kernel(const float* __restrict__ a, const float* __restrict__ b,
                            float* __restrict__ c, int n) {
  int i = blockIdx.x * blockDim.x + threadIdx.x;
  if (i < n) c[i] = a[i] + (i < HDIM ? b[i] : 0.0f);
}

// ---------------- async global->LDS 16B ----------------
__device__ __forceinline__ void g2l16(const void* g, void* l) {
  __builtin_amdgcn_global_load_lds(
      (const __attribute__((address_space(1))) unsigned int*)g,
      (__attribute__((address_space(3))) unsigned int*)l, 16, 0, 0);
}

// ---------------- Gi GEMM, split-split: C = (Ahi+Alo)(Bhi+Blo)^T + bias ----------------
__global__ __launch_bounds__(256) void gemm_bt(
    const unsigned short* __restrict__ Ahi,
    const unsigned short* __restrict__ Alo,
    const unsigned short* __restrict__ Bhi,
    const unsigned short* __restrict__ Blo,
    const float* __restrict__ bias,
    float* __restrict__ C,
    int M, int N, int K) {
  __shared__ unsigned short Ahs[128 * 32];
  __shared__ unsigned short Als[128 * 32];
  __shared__ unsigned short Bhs[128 * 32];
  __shared__ unsigned short Bls[128 * 32];
  const int tid  = threadIdx.x;
  const int w    = tid >> 6, lane = tid & 63;
  const int m16  = lane & 15, quad = lane >> 4;
  const int gn   = N >> 7;
  const int by   = blockIdx.x / gn, bx = blockIdx.x % gn;
  const int wm   = w & 1, wn = w >> 1;

  const int rr = lane >> 2;
  const int cc = lane & 3;
  const size_t ro0 = (size_t)((w*2+0)*16 + rr) * K + cc*8;
  const size_t ro1 = (size_t)((w*2+1)*16 + rr) * K + cc*8;
  const unsigned short* Ah0 = Ahi + (size_t)by*128*K + ro0;
  const unsigned short* Ah1 = Ahi + (size_t)by*128*K + ro1;
  const unsigned short* Al0 = Alo + (size_t)by*128*K + ro0;
  const unsigned short* Al1 = Alo + (size_t)by*128*K + ro1;
  const unsigned short* Bh0 = Bhi + (size_t)bx*128*K + ro0;
  const unsigned short* Bh1 = Bhi + (size_t)bx*128*K + ro1;
  const unsigned short* Bl0 = Blo + (size_t)bx*128*K + ro0;
  const unsigned short* Bl1 = Blo + (size_t)bx*128*K + ro1;

  floatx4 acc[4][4] = {};

  for (int k0 = 0; k0 < K; k0 += 32) {
    g2l16(Ah0 + k0, &Ahs[(w*2+0)*512]);
    g2l16(Ah1 + k0, &Ahs[(w*2+1)*512]);
    g2l16(Al0 + k0, &Als[(w*2+0)*512]);
    g2l16(Al1 + k0, &Als[(w*2+1)*512]);
    g2l16(Bh0 + k0, &Bhs[(w*2+0)*512]);
    g2l16(Bh1 + k0, &Bhs[(w*2+1)*512]);
    g2l16(Bl0 + k0, &Bls[(w*2+0)*512]);
    g2l16(Bl1 + k0, &Bls[(w*2+1)*512]);
    __syncthreads();

    bf16x8 ah[4], al[4], bh[4], bl[4];
#pragma unroll
    for (int mt = 0; mt < 4; ++mt) {
      ah[mt] = *(const bf16x8*)&Ahs[(wm*64 + mt*16 + m16)*32 + quad*8];
      al[mt] = *(const bf16x8*)&Als[(wm*64 + mt*16 + m16)*32 + quad*8];
    }
#pragma unroll
    for (int nt = 0; nt < 4; ++nt) {
      bh[nt] = *(const bf16x8*)&Bhs[(wn*64 + nt*16 + m16)*32 + quad*8];
      bl[nt] = *(const bf16x8*)&Bls[(wn*64 + nt*16 + m16)*32 + quad*8];
    }
#pragma unroll
    for (int mt = 0; mt < 4; ++mt)
#pragma unroll
      for (int nt = 0; nt < 4; ++nt) {
        acc[mt][nt] = __builtin_amdgcn_mfma_f32_16x16x32_bf16(ah[mt], bh[nt], acc[mt][nt], 0, 0, 0);
        acc[mt][nt] = __builtin_amdgcn_mfma_f32_16x16x32_bf16(al[mt], bh[nt], acc[mt][nt], 0, 0, 0);
        acc[mt][nt] = __builtin_amdgcn_mfma_f32_16x16x32_bf16(ah[mt], bl[nt], acc[mt][nt], 0, 0, 0);
      }
    __syncthreads();
  }

#pragma unroll
  for (int nt = 0; nt < 4; ++nt) {
    int col = bx*128 + wn*64 + nt*16 + m16;
    float bv = bias[col];
#pragma unroll
    for (int mt = 0; mt < 4; ++mt) {
      int row0 = by*128 + wm*64 + mt*16 + quad*4;
#pragma unroll
      for (int r = 0; r < 4; ++r)
        C[(size_t)(row0 + r)*N + col] = acc[mt][nt][r] + bv;
    }
  }
}

// ---- persistent recurrent kernel: FLAGLESS phase-stamped sync (speculative pull + verify) ----
// h element = u32: (bf16_hi << 16) | (bf16_lo & ~3) | (t & 3). Double buffer by t&1.
// NO FLAGS: consumers issue the payload load speculatively (overlapping Gi prefetch) and
// the 2-bit phase stamp validates each element. Stale kk-chunks (32B/lane) are reloaded
// with s_sleep backoff - unlike R1's full 512B/lane re-sweeps, reload traffic is tiny and
// the compiler's per-kk load->verify->MFMA pipeline stays intact (R8: VGPR 108, verify
// measured free). This removes the flag-store -> poll-detect MALL round-trip from the
// critical path: the first load issued after peer stores land validates instantly.
// SAFETY (skew<=1, per-cohort, no flags needed - R1 passed with this argument):
// wave (b,w) stores h_{t+1} (overwriting h_{t-1} slots, rows R_w x cols C_b) only after
// phase-verifying its h_t inputs (rows R_w, ALL cols) - a register data-dependency through
// the MFMAs. That proves every cohort-w wave stored h_t, hence finished reading h_{t-1}
// rows R_w. Phase ABA distance is 2 mod 4 -> stale always detectable. Initial phase 3
// (memset 0x03) is never expected (t=1 wants 0, t=2 wants 1).
// Weights in LDS (64KB/block): no compiler-issued global reloads competing with payload.
__global__ __launch_bounds__(256, 1) void mgu_recur(
    const float* __restrict__ Gi,            // [T*B, 1024] fp32 (f: both biases; n: b_ih only)
    const unsigned short* __restrict__ Whi,  // [1024, 512] bf16 hi
    const unsigned short* __restrict__ Wlo,  // [1024, 512] bf16 lo
    const float* __restrict__ bhh,           // [1024] fp32 (n-half used)
    unsigned int* __restrict__ hbuf,         // [2][64][512] u32 packed (memset 0x03 = phase 3)
    float* __restrict__ out) {               // [T*B, 512] fp32
  const int tid  = threadIdx.x;
  const int w    = tid >> 6, lane = tid & 63;
  const int m16  = lane & 15, quad = lane >> 4;
  const int j0   = blockIdx.x * 16;

  const float bnb = bhh[512 + j0 + m16];   // b_hh_n for this lane's output column

  // ---- weights -> LDS (one copy per block; same fragment layout for all 4 waves) ----
  __shared__ bf16x8 wlds[4][16][64];       // [fh,nh,fl,nl][kk][lane]
#pragma unroll
  for (int q = 0; q < 4; ++q) {
    int kk = w*4 + q;
    size_t of = (size_t)(j0 + m16)       * 512 + kk*32 + quad*8;
    size_t on = (size_t)(512 + j0 + m16) * 512 + kk*32 + quad*8;
    wlds[0][kk][lane] = *(const bf16x8*)&Whi[of];
    wlds[1][kk][lane] = *(const bf16x8*)&Whi[on];
    wlds[2][kk][lane] = *(const bf16x8*)&Wlo[of];
    wlds[3][kk][lane] = *(const bf16x8*)&Wlo[on];
  }
  __syncthreads();

  const int arow = w*16 + m16;   // batch row this lane reads for the A fragment

#pragma unroll 1
  for (int t = 0; t < T_STEPS; ++t) {
    // Gi prefetch (fp32, h-independent) — overlaps the speculative payload flight
    float gif[4], gin[4];
#pragma unroll
    for (int r = 0; r < 4; ++r) {
      size_t row = (size_t)t*64 + w*16 + quad*4 + r;
      gif[r] = Gi[row*1024 + j0 + m16];
      gin[r] = Gi[row*1024 + 512 + j0 + m16];
    }

    floatx4 accf0 = {}, accf1 = {}, accf2 = {};
    floatx4 accn0 = {}, accn1 = {}, accn2 = {};

    if (t > 0) {
      const unsigned int ph = (unsigned int)((t-1) & 3);
      const unsigned long long* hrow =
          (const unsigned long long*)(hbuf + (size_t)((t-1)&1)*BATCH*HDIM)
          + (size_t)arow*256 + quad*4;   // row stride 256 u64; col base quad*8 elems

      // speculative bulk payload load (no gate: phase stamps validate)
      unsigned long long pk[16][4];
#pragma unroll
      for (int kk = 0; kk < 16; ++kk)
#pragma unroll
        for (int i = 0; i < 4; ++i)
          pk[kk][i] = __hip_atomic_load(hrow + kk*16 + i,
                        __ATOMIC_RELAXED, __HIP_MEMORY_SCOPE_AGENT);

      // per-kk: verify 8 phase fields, reload just this 32B chunk if stale; unpack; 6 MFMA
#pragma unroll
      for (int kk = 0; kk < 16; ++kk) {
        {
          int sp = 0;
          for (;;) {
            unsigned int bad =
                (((unsigned int)pk[kk][0] ^ ph) | ((unsigned int)(pk[kk][0] >> 32) ^ ph) |
                 ((unsigned int)pk[kk][1] ^ ph) | ((unsigned int)(pk[kk][1] >> 32) ^ ph) |
                 ((unsigned int)pk[kk][2] ^ ph) | ((unsigned int)(pk[kk][2] >> 32) ^ ph) |
                 ((unsigned int)pk[kk][3] ^ ph) | ((unsigned int)(pk[kk][3] >> 32) ^ ph)) & 3u;
            if (!__any((int)bad)) break;
            if (++sp >= (1 << 16)) break;   // cap: wrong results, not a hang
            __builtin_amdgcn_s_sleep(1);
#pragma unroll
            for (int i = 0; i < 4; ++i)
              pk[kk][i] = __hip_atomic_load(hrow + kk*16 + i,
                            __ATOMIC_RELAXED, __HIP_MEMORY_SCOPE_AGENT);
          }
        }
        unsigned int e0 = (unsigned int)pk[kk][0], e1 = (unsigned int)(pk[kk][0] >> 32);
        unsigned int e2 = (unsigned int)pk[kk][1], e3 = (unsigned int)(pk[kk][1] >> 32);
        unsigned int e4 = (unsigned int)pk[kk][2], e5 = (unsigned int)(pk[kk][2] >> 32);
        unsigned int e6 = (unsigned int)pk[kk][3], e7 = (unsigned int)(pk[kk][3] >> 32);
        u32x4 h4 = { __builtin_amdgcn_perm(e1, e0, 0x07060302u),
                     __builtin_amdgcn_perm(e3, e2, 0x07060302u),
                     __builtin_amdgcn_perm(e5, e4, 0x07060302u),
                     __builtin_amdgcn_perm(e7, e6, 0x07060302u) };
        u32x4 l4 = { __builtin_amdgcn_perm(e1, e0, 0x05040100u) & 0xFFFCFFFCu,
                     __builtin_amdgcn_perm(e3, e2, 0x05040100u) & 0xFFFCFFFCu,
                     __builtin_amdgcn_perm(e5, e4, 0x05040100u) & 0xFFFCFFFCu,
                     __builtin_amdgcn_perm(e7, e6, 0x05040100u) & 0xFFFCFFFCu };
        bf16x8 ah = __builtin_bit_cast(bf16x8, h4);
        bf16x8 al = __builtin_bit_cast(bf16x8, l4);
        bf16x8 fh = wlds[0][kk][lane], nh = wlds[1][kk][lane];
        bf16x8 fl = wlds[2][kk][lane], nl = wlds[3][kk][lane];
        accf0 = __builtin_amdgcn_mfma_f32_16x16x32_bf16(ah, fh, accf0, 0, 0, 0);
        accf1 = __builtin_amdgcn_mfma_f32_16x16x32_bf16(al, fh, accf1, 0, 0, 0);
        accf2 = __builtin_amdgcn_mfma_f32_16x16x32_bf16(ah, fl, accf2, 0, 0, 0);
        accn0 = __builtin_amdgcn_mfma_f32_16x16x32_bf16(ah, nh, accn0, 0, 0, 0);
        accn1 = __builtin_amdgcn_mfma_f32_16x16x32_bf16(al, nh, accn1, 0, 0, 0);
        accn2 = __builtin_amdgcn_mfma_f32_16x16x32_bf16(ah, nl, accn2, 0, 0, 0);
      }
    }

    // gates + nonlinearity (fp32); phase-stamped h stores (these ARE the sync signal)
    const unsigned int phw = (unsigned int)(t & 3);
    unsigned int* hcur = hbuf + (size_t)(t&1)*BATCH*HDIM;
    float hv[4];
#pragma unroll
    for (int r = 0; r < 4; ++r) {
      float xf = gif[r] + (accf0[r] + accf1[r] + accf2[r]);
      float f  = 1.0f / (1.0f + __expf(-xf));
      float xn = gin[r] + f * (accn0[r] + accn1[r] + accn2[r] + bnb);
      float ex = __expf(-2.0f * xn);
      float h  = (1.0f - ex) / (1.0f + ex);    // tanh
      hv[r] = h;
      unsigned short hh = f2bf(h);
      unsigned short hl = f2bf(h - bf2f(hh));
      unsigned int packed = ((unsigned int)hh << 16) | ((unsigned int)hl & 0xFFFCu) | phw;
      int row = w*16 + quad*4 + r;
      __hip_atomic_store(hcur + (size_t)row*512 + j0 + m16, packed,
                         __ATOMIC_RELAXED, __HIP_MEMORY_SCOPE_AGENT);
    }

    // out store after h stores: off the inter-wave critical path
#pragma unroll
    for (int r = 0; r < 4; ++r) {
      int row = w*16 + quad*4 + r;
      __builtin_nontemporal_store(hv[r], &out[((size_t)t*64 + row)*512 + j0 + m16]);
    }
  }
}

// ---------------- launch ----------------
extern "C" void kernel_launch(void* const* d_in, const int* in_sizes, int n_in,
                              void* d_out, int out_size, void* d_ws, size_t ws_size,
                              hipStream_t stream) {
  (void)in_sizes; (void)n_in; (void)out_size; (void)ws_size;
  const float* X   = (const float*)d_in[0];   // [512,64,512]
  const float* Wih = (const float*)d_in[1];   // [1024,512]
  const float* Whh = (const float*)d_in[2];   // [1024,512]
  const float* bih = (const float*)d_in[3];   // [1024]
  const float* bhh = (const float*)d_in[4];   // [1024]
  float* out = (float*)d_out;

  const int TB = T_STEPS * BATCH;  // 32768

  // workspace layout (~207 MB)
  unsigned short* Xhi    = (unsigned short*)d_ws;                    // TB*IDIM bf16
  unsigned short* Xlo    = Xhi   + (size_t)TB * IDIM;
  unsigned short* WihHi  = Xlo   + (size_t)TB * IDIM;                // NGATE*IDIM
  unsigned short* WihLo  = WihHi + (size_t)NGATE * IDIM;
  unsigned short* WhhHi  = WihLo + (size_t)NGATE * IDIM;             // NGATE*HDIM
  unsigned short* WhhLo  = WhhHi + (size_t)NGATE * HDIM;
  float*          biasc  = (float*)(WhhLo + (size_t)NGATE * HDIM);   // NGATE
  float*          Gi     = biasc + NGATE;                            // TB*NGATE fp32
  unsigned int*   hbuf   = (unsigned int*)(Gi + (size_t)TB * NGATE); // [2][64][512] u32

  // hbuf -> phase 3 (0x03030303): never a valid expected phase (t=1 expects 0, t=2 expects 1)
  (void)hipMemsetAsync(hbuf, 0x03, (size_t)2 * BATCH * HDIM * sizeof(unsigned int), stream);

  int n4;
  n4 = TB * IDIM / 4;
  cvt_split_kernel<<<n4/256, 256, 0, stream>>>((const float4*)X, (ushort4*)Xhi, (ushort4*)Xlo, n4);
  n4 = NGATE * IDIM / 4;
  cvt_split_kernel<<<n4/256, 256, 0, stream>>>((const float4*)Wih, (ushort4*)WihHi, (ushort4*)WihLo, n4);
  n4 = NGATE * HDIM / 4;
  cvt_split_kernel<<<n4/256, 256, 0, stream>>>((const float4*)Whh, (ushort4*)WhhHi, (ushort4*)WhhLo, n4);
  bias_kernel<<<4, 256, 0, stream>>>(bih, bhh, biasc, NGATE);

  gemm_bt<<<(TB/128)*(NGATE/128), 256, 0, stream>>>(Xhi, Xlo, WihHi, WihLo, biasc, Gi, TB, NGATE, IDIM);

  mgu_recur<<<RBLOCKS, 256, 0, stream>>>(Gi, WhhHi, WhhLo, bhh, hbuf, out);
}

// Round 10
// 2942.891 us; speedup vs baseline: 2.8643x; 2.8643x over previous
//
#include <hip/hip_runtime.h>
#include <stdint.h>

typedef __bf16 bf16x8 __attribute__((ext_vector_type(8)));
typedef float floatx4 __attribute__((ext_vector_type(4)));
typedef unsigned int u32x4 __attribute__((ext_vector_type(4)));

#define T_STEPS 512
#define BATCH   64
#define HDIM    512
#define NGATE   1024   // 2*H
#define IDIM    512
#define RBLOCKS 32     // recurrent blocks, 16 cols each

__device__ __forceinline__ unsigned short f2bf(float f) {
  unsigned int u = __builtin_bit_cast(unsigned int, f);
  u += 0x7fffu + ((u >> 16) & 1u);
  return (unsigned short)(u >> 16);
}
__device__ __forceinline__ float bf2f(unsigned short s) {
  unsigned int u = ((unsigned int)s) << 16;
  return __builtin_bit_cast(float, u);
}

// ---------------- fp32 -> bf16 hi + lo residual ----------------
__global__ void cvt_split_kernel(const float4* __restrict__ src,
                                 ushort4* __restrict__ hi, ushort4* __restrict__ lo, int n4) {
  int i = blockIdx.x * blockDim.x + threadIdx.x;
  if (i >= n4) return;
  float4 v = src[i];
  ushort4 h, l;
  h.x = f2bf(v.x); l.x = f2bf(v.x - bf2f(h.x));
  h.y = f2bf(v.y); l.y = f2bf(v.y - bf2f(h.y));
  h.z = f2bf(v.z); l.z = f2bf(v.z - bf2f(h.z));
  h.w = f2bf(v.w); l.w = f2bf(v.w - bf2f(h.w));
  hi[i] = h; lo[i] = l;
}

// biasc[i] = bih[i] + (i < H ? bhh[i] : 0)
__global__ void bias_kernel(const float* __restrict__ a, const float* __restrict__ b,
                            float* __restrict__ c, int n) {
  int i = blockIdx.x * blockDim.x + threadIdx.x;
  if (i < n) c[i] = a[i] + (i < HDIM ? b[i] : 0.0f);
}

// ---------------- async global->LDS 16B ----------------
__device__ __forceinline__ void g2l16(const void* g, void* l) {
  __builtin_amdgcn_global_load_lds(
      (const __attribute__((address_space(1))) unsigned int*)g,
      (__attribute__((address_space(3))) unsigned int*)l, 16, 0, 0);
}

// ---------------- Gi GEMM, split-split: C = (Ahi+Alo)(Bhi+Blo)^T + bias ----------------
__global__ __launch_bounds__(256) void gemm_bt(
    const unsigned short* __restrict__ Ahi,
    const unsigned short* __restrict__ Alo,
    const unsigned short* __restrict__ Bhi,
    const unsigned short* __restrict__ Blo,
    const float* __restrict__ bias,
    float* __restrict__ C,
    int M, int N, int K) {
  __shared__ unsigned short Ahs[128 * 32];
  __shared__ unsigned short Als[128 * 32];
  __shared__ unsigned short Bhs[128 * 32];
  __shared__ unsigned short Bls[128 * 32];
  const int tid  = threadIdx.x;
  const int w    = tid >> 6, lane = tid & 63;
  const int m16  = lane & 15, quad = lane >> 4;
  const int gn   = N >> 7;
  const int by   = blockIdx.x / gn, bx = blockIdx.x % gn;
  const int wm   = w & 1, wn = w >> 1;

  const int rr = lane >> 2;
  const int cc = lane & 3;
  const size_t ro0 = (size_t)((w*2+0)*16 + rr) * K + cc*8;
  const size_t ro1 = (size_t)((w*2+1)*16 + rr) * K + cc*8;
  const unsigned short* Ah0 = Ahi + (size_t)by*128*K + ro0;
  const unsigned short* Ah1 = Ahi + (size_t)by*128*K + ro1;
  const unsigned short* Al0 = Alo + (size_t)by*128*K + ro0;
  const unsigned short* Al1 = Alo + (size_t)by*128*K + ro1;
  const unsigned short* Bh0 = Bhi + (size_t)bx*128*K + ro0;
  const unsigned short* Bh1 = Bhi + (size_t)bx*128*K + ro1;
  const unsigned short* Bl0 = Blo + (size_t)bx*128*K + ro0;
  const unsigned short* Bl1 = Blo + (size_t)bx*128*K + ro1;

  floatx4 acc[4][4] = {};

  for (int k0 = 0; k0 < K; k0 += 32) {
    g2l16(Ah0 + k0, &Ahs[(w*2+0)*512]);
    g2l16(Ah1 + k0, &Ahs[(w*2+1)*512]);
    g2l16(Al0 + k0, &Als[(w*2+0)*512]);
    g2l16(Al1 + k0, &Als[(w*2+1)*512]);
    g2l16(Bh0 + k0, &Bhs[(w*2+0)*512]);
    g2l16(Bh1 + k0, &Bhs[(w*2+1)*512]);
    g2l16(Bl0 + k0, &Bls[(w*2+0)*512]);
    g2l16(Bl1 + k0, &Bls[(w*2+1)*512]);
    __syncthreads();

    bf16x8 ah[4], al[4], bh[4], bl[4];
#pragma unroll
    for (int mt = 0; mt < 4; ++mt) {
      ah[mt] = *(const bf16x8*)&Ahs[(wm*64 + mt*16 + m16)*32 + quad*8];
      al[mt] = *(const bf16x8*)&Als[(wm*64 + mt*16 + m16)*32 + quad*8];
    }
#pragma unroll
    for (int nt = 0; nt < 4; ++nt) {
      bh[nt] = *(const bf16x8*)&Bhs[(wn*64 + nt*16 + m16)*32 + quad*8];
      bl[nt] = *(const bf16x8*)&Bls[(wn*64 + nt*16 + m16)*32 + quad*8];
    }
#pragma unroll
    for (int mt = 0; mt < 4; ++mt)
#pragma unroll
      for (int nt = 0; nt < 4; ++nt) {
        acc[mt][nt] = __builtin_amdgcn_mfma_f32_16x16x32_bf16(ah[mt], bh[nt], acc[mt][nt], 0, 0, 0);
        acc[mt][nt] = __builtin_amdgcn_mfma_f32_16x16x32_bf16(al[mt], bh[nt], acc[mt][nt], 0, 0, 0);
        acc[mt][nt] = __builtin_amdgcn_mfma_f32_16x16x32_bf16(ah[mt], bl[nt], acc[mt][nt], 0, 0, 0);
      }
    __syncthreads();
  }

#pragma unroll
  for (int nt = 0; nt < 4; ++nt) {
    int col = bx*128 + wn*64 + nt*16 + m16;
    float bv = bias[col];
#pragma unroll
    for (int mt = 0; mt < 4; ++mt) {
      int row0 = by*128 + wm*64 + mt*16 + quad*4;
#pragma unroll
      for (int r = 0; r < 4; ++r)
        C[(size_t)(row0 + r)*N + col] = acc[mt][nt][r] + bv;
    }
  }
}

// ---- persistent recurrent kernel: R8 protocol + wide plain-load payload pull ----
// Protocol identical to R8 (session best): wave-cohort hint flags (no producer drain),
// phase-stamped h (u32 = hi<<16 | (lo&~3) | t&3), per-kk verify, LDS weights.
// CHANGE vs R8: the payload first-attempt uses plain global_load_dwordx4 with sc0 sc1
// (L1+L2 bypass -> MALL-coherent read, non-atomic path, 16B/op instead of 8B atomic ops)
// hand-pipelined 2 batches deep with counted vmcnt(8). This halves MALL line touches
// for the h broadcast pull (the suspected ~9us/step throughput term).
// Counted-vmcnt soundness (R5 lesson): an explicit vmcnt(0) right after the flag poll
// drains ALL compiler VMEM (Gi prefetch etc); weights are in LDS (lgkmcnt); so the only
// VMEM in flight during the counted waits are these asm loads. sched_barrier(0) after
// each wait stops hipcc hoisting dependent VALU/MFMA above it (rule #18).
// Verify-retry uses the PROVEN __hip_atomic_load path; its compiler-emitted waits are
// newest-load-based -> always safe; a retry draining the queue only makes later counted
// waits pass earlier with the target batch complete (safe direction). If sc0 sc1 load
// semantics were wrong, every chunk fails verify and falls back to atomic loads:
// bounded ~R8 cost, never a correctness loss.
#define WAITN(n) do { asm volatile("s_waitcnt vmcnt(" #n ")" ::: "memory"); \
                      __builtin_amdgcn_sched_barrier(0); } while (0)

#define BISSUE(q0,q1,q2,q3,q4,q5,q6,q7, O0,O1,O2,O3,O4,O5,O6,O7) \
  asm volatile( \
    "global_load_dwordx4 %0, %8, off offset:" O0 " sc0 sc1\n\t" \
    "global_load_dwordx4 %1, %8, off offset:" O1 " sc0 sc1\n\t" \
    "global_load_dwordx4 %2, %8, off offset:" O2 " sc0 sc1\n\t" \
    "global_load_dwordx4 %3, %8, off offset:" O3 " sc0 sc1\n\t" \
    "global_load_dwordx4 %4, %8, off offset:" O4 " sc0 sc1\n\t" \
    "global_load_dwordx4 %5, %8, off offset:" O5 " sc0 sc1\n\t" \
    "global_load_dwordx4 %6, %8, off offset:" O6 " sc0 sc1\n\t" \
    "global_load_dwordx4 %7, %8, off offset:" O7 " sc0 sc1" \
    : "=&v"(q0), "=&v"(q1), "=&v"(q2), "=&v"(q3), \
      "=&v"(q4), "=&v"(q5), "=&v"(q6), "=&v"(q7) \
    : "v"(hb) : "memory")

#define PHBAD(q0,q1) ((( ((q0).x ^ ph) | ((q0).y ^ ph) | ((q0).z ^ ph) | ((q0).w ^ ph) | \
                         ((q1).x ^ ph) | ((q1).y ^ ph) | ((q1).z ^ ph) | ((q1).w ^ ph) )) & 3u)

#define VCONS(q0, q1, kkc) do { \
    unsigned int bad_ = PHBAD(q0, q1); \
    if (__builtin_expect(__any((int)bad_) != 0, 0)) { \
      const unsigned long long* rp_ = (const unsigned long long*)hb + (kkc)*16; \
      int sp_ = 0; \
      for (;;) { \
        unsigned long long w0_ = __hip_atomic_load(rp_ + 0, __ATOMIC_RELAXED, __HIP_MEMORY_SCOPE_AGENT); \
        unsigned long long w1_ = __hip_atomic_load(rp_ + 1, __ATOMIC_RELAXED, __HIP_MEMORY_SCOPE_AGENT); \
        unsigned long long w2_ = __hip_atomic_load(rp_ + 2, __ATOMIC_RELAXED, __HIP_MEMORY_SCOPE_AGENT); \
        unsigned long long w3_ = __hip_atomic_load(rp_ + 3, __ATOMIC_RELAXED, __HIP_MEMORY_SCOPE_AGENT); \
        (q0).x = (unsigned int)w0_; (q0).y = (unsigned int)(w0_ >> 32); \
        (q0).z = (unsigned int)w1_; (q0).w = (unsigned int)(w1_ >> 32); \
        (q1).x = (unsigned int)w2_; (q1).y = (unsigned int)(w2_ >> 32); \
        (q1).z = (unsigned int)w3_; (q1).w = (unsigned int)(w3_ >> 32); \
        if (!__any((int)PHBAD(q0, q1))) break; \
        if (++sp_ >= (1 << 16)) break;   /* cap: wrong results, not a hang */ \
        __builtin_amdgcn_s_sleep(1); \
      } \
    } \
    u32x4 h4_ = { __builtin_amdgcn_perm((q0).y, (q0).x, 0x07060302u), \
                  __builtin_amdgcn_perm((q0).w, (q0).z, 0x07060302u), \
                  __builtin_amdgcn_perm((q1).y, (q1).x, 0x07060302u), \
                  __builtin_amdgcn_perm((q1).w, (q1).z, 0x07060302u) }; \
    u32x4 l4_ = { __builtin_amdgcn_perm((q0).y, (q0).x, 0x05040100u) & 0xFFFCFFFCu, \
                  __builtin_amdgcn_perm((q0).w, (q0).z, 0x05040100u) & 0xFFFCFFFCu, \
                  __builtin_amdgcn_perm((q1).y, (q1).x, 0x05040100u) & 0xFFFCFFFCu, \
                  __builtin_amdgcn_perm((q1).w, (q1).z, 0x05040100u) & 0xFFFCFFFCu }; \
    bf16x8 ah_ = __builtin_bit_cast(bf16x8, h4_); \
    bf16x8 al_ = __builtin_bit_cast(bf16x8, l4_); \
    bf16x8 fh_ = wlds[0][kkc][lane], nh_ = wlds[1][kkc][lane]; \
    bf16x8 fl_ = wlds[2][kkc][lane], nl_ = wlds[3][kkc][lane]; \
    accf0 = __builtin_amdgcn_mfma_f32_16x16x32_bf16(ah_, fh_, accf0, 0, 0, 0); \
    accf1 = __builtin_amdgcn_mfma_f32_16x16x32_bf16(al_, fh_, accf1, 0, 0, 0); \
    accf2 = __builtin_amdgcn_mfma_f32_16x16x32_bf16(ah_, fl_, accf2, 0, 0, 0); \
    accn0 = __builtin_amdgcn_mfma_f32_16x16x32_bf16(ah_, nh_, accn0, 0, 0, 0); \
    accn1 = __builtin_amdgcn_mfma_f32_16x16x32_bf16(al_, nh_, accn1, 0, 0, 0); \
    accn2 = __builtin_amdgcn_mfma_f32_16x16x32_bf16(ah_, nl_, accn2, 0, 0, 0); \
  } while (0)

__global__ __launch_bounds__(256, 1) void mgu_recur(
    const float* __restrict__ Gi,            // [T*B, 1024] fp32 (f: both biases; n: b_ih only)
    const unsigned short* __restrict__ Whi,  // [1024, 512] bf16 hi
    const unsigned short* __restrict__ Wlo,  // [1024, 512] bf16 lo
    const float* __restrict__ bhh,           // [1024] fp32 (n-half used)
    unsigned int* __restrict__ hbuf,         // [2][64][512] u32 packed (memset 0x03 = phase 3)
    unsigned int* __restrict__ flags,        // 128 words, stride 32 (zeroed)
    float* __restrict__ out) {               // [T*B, 512] fp32
  const int tid  = threadIdx.x;
  const int w    = tid >> 6, lane = tid & 63;
  const int m16  = lane & 15, quad = lane >> 4;
  const int j0   = blockIdx.x * 16;

  const float bnb = bhh[512 + j0 + m16];   // b_hh_n for this lane's output column

  // ---- weights -> LDS (one copy per block; same fragment layout for all 4 waves) ----
  __shared__ bf16x8 wlds[4][16][64];       // [fh,nh,fl,nl][kk][lane]
#pragma unroll
  for (int q = 0; q < 4; ++q) {
    int kk = w*4 + q;
    size_t of = (size_t)(j0 + m16)       * 512 + kk*32 + quad*8;
    size_t on = (size_t)(512 + j0 + m16) * 512 + kk*32 + quad*8;
    wlds[0][kk][lane] = *(const bf16x8*)&Whi[of];
    wlds[1][kk][lane] = *(const bf16x8*)&Whi[on];
    wlds[2][kk][lane] = *(const bf16x8*)&Wlo[of];
    wlds[3][kk][lane] = *(const bf16x8*)&Wlo[on];
  }
  __syncthreads();

  const int arow = w*16 + m16;   // batch row this lane reads for the A fragment

  unsigned int* myflag = flags + (blockIdx.x*4 + w) * 32;
  const unsigned int* pollflag = flags + ((lane & 31)*4 + w) * 32;  // cohort w, block lane&31

#pragma unroll 1
  for (int t = 0; t < T_STEPS; ++t) {
    // Gi prefetch (fp32, h-independent) — overlaps the flag poll
    float gif[4], gin[4];
#pragma unroll
    for (int r = 0; r < 4; ++r) {
      size_t row = (size_t)t*64 + w*16 + quad*4 + r;
      gif[r] = Gi[row*1024 + j0 + m16];
      gin[r] = Gi[row*1024 + 512 + j0 + m16];
    }

    floatx4 accf0 = {}, accf1 = {}, accf2 = {};
    floatx4 accn0 = {}, accn1 = {}, accn2 = {};

    if (t > 0) {
      // cohort HINT poll: 1 word/lane, tight (R8-proven)
      unsigned int fv;
      do {
        fv = __hip_atomic_load(pollflag, __ATOMIC_RELAXED, __HIP_MEMORY_SCOPE_AGENT);
      } while (__any((int)(fv < (unsigned int)t)));

      const unsigned int ph = (unsigned int)((t-1) & 3);
      // lane's 512B row-slice base: contiguous 32B per kk at +kk*128B
      const unsigned int* hb = hbuf + (size_t)((t-1)&1)*BATCH*HDIM
                             + (size_t)arow*512 + quad*8;

      // drain ALL compiler VMEM so counted vmcnt below sees only our asm loads
      asm volatile("s_waitcnt vmcnt(0)" ::: "memory");
      __builtin_amdgcn_sched_barrier(0);

      u32x4 a0,a1,a2,a3,a4,a5,a6,a7, b0,b1,b2,b3,b4,b5,b6,b7;
      BISSUE(a0,a1,a2,a3,a4,a5,a6,a7, "0","16","128","144","256","272","384","400");
      BISSUE(b0,b1,b2,b3,b4,b5,b6,b7, "512","528","640","656","768","784","896","912");
      WAITN(8);   // batch A (kk 0..3) complete
      VCONS(a0,a1,0);  VCONS(a2,a3,1);  VCONS(a4,a5,2);  VCONS(a6,a7,3);
      BISSUE(a0,a1,a2,a3,a4,a5,a6,a7, "1024","1040","1152","1168","1280","1296","1408","1424");
      WAITN(8);   // batch B (kk 4..7) complete
      VCONS(b0,b1,4);  VCONS(b2,b3,5);  VCONS(b4,b5,6);  VCONS(b6,b7,7);
      BISSUE(b0,b1,b2,b3,b4,b5,b6,b7, "1536","1552","1664","1680","1792","1808","1920","1936");
      WAITN(8);   // batch A2 (kk 8..11) complete
      VCONS(a0,a1,8);  VCONS(a2,a3,9);  VCONS(a4,a5,10); VCONS(a6,a7,11);
      WAITN(0);   // batch B2 (kk 12..15) complete
      VCONS(b0,b1,12); VCONS(b2,b3,13); VCONS(b4,b5,14); VCONS(b6,b7,15);
    }

    // gates + nonlinearity (fp32); phase-stamped h stores, then HINT flag (no drain)
    const unsigned int phw = (unsigned int)(t & 3);
    unsigned int* hcur = hbuf + (size_t)(t&1)*BATCH*HDIM;
    float hv[4];
#pragma unroll
    for (int r = 0; r < 4; ++r) {
      float xf = gif[r] + (accf0[r] + accf1[r] + accf2[r]);
      float f  = 1.0f / (1.0f + __expf(-xf));
      float xn = gin[r] + f * (accn0[r] + accn1[r] + accn2[r] + bnb);
      float ex = __expf(-2.0f * xn);
      float h  = (1.0f - ex) / (1.0f + ex);    // tanh
      hv[r] = h;
      unsigned short hh = f2bf(h);
      unsigned short hl = f2bf(h - bf2f(hh));
      unsigned int packed = ((unsigned int)hh << 16) | ((unsigned int)hl & 0xFFFCu) | phw;
      int row = w*16 + quad*4 + r;
      __hip_atomic_store(hcur + (size_t)row*512 + j0 + m16, packed,
                         __ATOMIC_RELAXED, __HIP_MEMORY_SCOPE_AGENT);
    }

    // HINT flag: issued right after the h stores, NO vmcnt drain (phase bits carry validity)
    if (lane == 0)
      __hip_atomic_store(myflag, (unsigned int)(t + 1),
                         __ATOMIC_RELAXED, __HIP_MEMORY_SCOPE_AGENT);

    // out store AFTER flag: off the inter-wave critical path
#pragma unroll
    for (int r = 0; r < 4; ++r) {
      int row = w*16 + quad*4 + r;
      __builtin_nontemporal_store(hv[r], &out[((size_t)t*64 + row)*512 + j0 + m16]);
    }
  }
}

// ---------------- launch ----------------
extern "C" void kernel_launch(void* const* d_in, const int* in_sizes, int n_in,
                              void* d_out, int out_size, void* d_ws, size_t ws_size,
                              hipStream_t stream) {
  (void)in_sizes; (void)n_in; (void)out_size; (void)ws_size;
  const float* X   = (const float*)d_in[0];   // [512,64,512]
  const float* Wih = (const float*)d_in[1];   // [1024,512]
  const float* Whh = (const float*)d_in[2];   // [1024,512]
  const float* bih = (const float*)d_in[3];   // [1024]
  const float* bhh = (const float*)d_in[4];   // [1024]
  float* out = (float*)d_out;

  const int TB = T_STEPS * BATCH;  // 32768

  // workspace layout (~207 MB)
  unsigned short* Xhi    = (unsigned short*)d_ws;                    // TB*IDIM bf16
  unsigned short* Xlo    = Xhi   + (size_t)TB * IDIM;
  unsigned short* WihHi  = Xlo   + (size_t)TB * IDIM;                // NGATE*IDIM
  unsigned short* WihLo  = WihHi + (size_t)NGATE * IDIM;
  unsigned short* WhhHi  = WihLo + (size_t)NGATE * IDIM;             // NGATE*HDIM
  unsigned short* WhhLo  = WhhHi + (size_t)NGATE * HDIM;
  float*          biasc  = (float*)(WhhLo + (size_t)NGATE * HDIM);   // NGATE
  float*          Gi     = biasc + NGATE;                            // TB*NGATE fp32
  unsigned int*   hbuf   = (unsigned int*)(Gi + (size_t)TB * NGATE); // [2][64][512] u32
  unsigned int*   flags  = hbuf + (size_t)2 * BATCH * HDIM;          // 128 x stride-32 u32

  // hbuf -> phase 3 (0x03030303): never a valid expected phase (t=1 expects 0, t=2 expects 1)
  (void)hipMemsetAsync(hbuf, 0x03, (size_t)2 * BATCH * HDIM * sizeof(unsigned int), stream);
  (void)hipMemsetAsync(flags, 0, (size_t)RBLOCKS * 4 * 32 * sizeof(unsigned int), stream);

  int n4;
  n4 = TB * IDIM / 4;
  cvt_split_kernel<<<n4/256, 256, 0, stream>>>((const float4*)X, (ushort4*)Xhi, (ushort4*)Xlo, n4);
  n4 = NGATE * IDIM / 4;
  cvt_split_kernel<<<n4/256, 256, 0, stream>>>((const float4*)Wih, (ushort4*)WihHi, (ushort4*)WihLo, n4);
  n4 = NGATE * HDIM / 4;
  cvt_split_kernel<<<n4/256, 256, 0, stream>>>((const float4*)Whh, (ushort4*)WhhHi, (ushort4*)WhhLo, n4);
  bias_kernel<<<4, 256, 0, stream>>>(bih, bhh, biasc, NGATE);

  gemm_bt<<<(TB/128)*(NGATE/128), 256, 0, stream>>>(Xhi, Xlo, WihHi, WihLo, biasc, Gi, TB, NGATE, IDIM);

  mgu_recur<<<RBLOCKS, 256, 0, stream>>>(Gi, WhhHi, WhhLo, bhh, hbuf, flags, out);
}